// Round 3
// baseline (227.772 us; speedup 1.0000x reference)
//
#include <hip/hip_runtime.h>
#include <math.h>

typedef __attribute__((ext_vector_type(8))) short short8;
typedef __attribute__((ext_vector_type(4))) float f32x4;
typedef __attribute__((ext_vector_type(16))) float f32x16;

#define PSTRIDE 4160          // partials row stride in floats (non-pow2)

// round-to-nearest-even fp32 -> bf16 bits (validated numerics, keep exact)
__device__ __forceinline__ unsigned int bf16_rn(float x) {
    unsigned int u = __float_as_uint(x);
    return (u + 0x7FFFu + ((u >> 16) & 1u)) >> 16;
}

__device__ __forceinline__ short8 cvt8(float4 a, float4 b) {
    short8 h;
    h[0] = (short)bf16_rn(a.x); h[1] = (short)bf16_rn(a.y);
    h[2] = (short)bf16_rn(a.z); h[3] = (short)bf16_rn(a.w);
    h[4] = (short)bf16_rn(b.x); h[5] = (short)bf16_rn(b.y);
    h[6] = (short)bf16_rn(b.z); h[7] = (short)bf16_rn(b.w);
    return h;
}

// ---------------------------------------------------------------------------
// Kernel 1 (gram + CE fused): 512 threads (8 waves).
// CE blocks first (blk < ceCount): per-row cross-entropy + logits copy.
// Gram blocks: one block per (feature, 512-k chunk); wave w = (khalf h=w>>2,
// quadrant q=w&3). Each wave computes its 32x32 quadrant over a 256-k window
// with mfma_f32_32x32x16_bf16, fragments loaded DIRECTLY from global fp32
// (2x float4/operand, 32 rows x 64 B line-coalesced) and converted in-reg.
// No staging LDS -> high occupancy (the R0-R2 evidence: 8 waves/CU caps the
// miss path at ~1.2 TB/s regardless of per-wave bytes in flight; repack at
// ~32 waves hit ~5 TB/s). k-half pairs reduce via 16 KB LDS, then write
// the 64x64 partial Gram.
// ---------------------------------------------------------------------------
__global__ __launch_bounds__(512, 6) void gram_ce_kernel(
    const float* __restrict__ A, const float* __restrict__ B,
    float* __restrict__ partials, int nfA, int nfB,
    const float* __restrict__ logits, const int* __restrict__ target,
    float* __restrict__ out_copy, float* __restrict__ ce_rows, int ceCount)
{
    __shared__ float smem[4096];   // gram: 4x[32][32] quadrant buf; CE: red
    const int t = threadIdx.x;

    if ((int)blockIdx.x < ceCount) {
        // ------------------ CE block ------------------
        const int row = blockIdx.x;
        const float* x = logits + row * 1000;
        float m = -INFINITY;
        for (int i = t; i < 1000; i += 512) {
            float v = x[i];
            out_copy[row * 1000 + i] = v;
            m = fmaxf(m, v);
        }
        smem[t] = m; __syncthreads();
        for (int s = 256; s > 0; s >>= 1) {
            if (t < s) smem[t] = fmaxf(smem[t], smem[t + s]);
            __syncthreads();
        }
        m = smem[0];
        __syncthreads();
        float ssum = 0.f;
        for (int i = t; i < 1000; i += 512) ssum += expf(x[i] - m);
        smem[t] = ssum; __syncthreads();
        for (int s = 256; s > 0; s >>= 1) {
            if (t < s) smem[t] += smem[t + s];
            __syncthreads();
        }
        if (t == 0) {
            double lse = (double)m + log((double)smem[0]);
            int tg = target[row];
            ce_rows[row] = (float)(-((double)x[tg] - lse));
        }
        return;
    }

    // ------------------ gram block ------------------
    const int gb = blockIdx.x - ceCount;
    const int uA = nfA * 128;              // A chunk-blocks (128 x 512k /feat)
    const float* xf;
    int c, D;
    if (gb < uA) {
        int f = gb >> 7; c = gb & 127; D = 65536;
        xf = A + (size_t)f * 64 * 65536;
    } else {
        int v = gb - uA;
        int f = v >> 6; c = v & 63; D = 32768;
        xf = B + (size_t)f * 64 * 32768;
    }

    const int wave = t >> 6, lane = t & 63;
    const int q = wave & 3, h = wave >> 2;
    const int wr = q >> 1, wc = q & 1;
    const int lr = lane & 31, hi = lane >> 5;
    const int k0 = c * 512 + h * 256 + hi * 8;

    const float* pA = xf + (size_t)(wr * 32 + lr) * D + k0;
    const float* pB = xf + (size_t)(wc * 32 + lr) * D + k0;

    f32x16 acc = (f32x16)0.f;
    if (wr == wc) {
#pragma unroll
        for (int s = 0; s < 16; ++s) {
            float4 a0 = *(const float4*)(pA + s * 16);
            float4 a1 = *(const float4*)(pA + s * 16 + 4);
            short8 fa = cvt8(a0, a1);
            acc = __builtin_amdgcn_mfma_f32_32x32x16_bf16(fa, fa, acc, 0, 0, 0);
        }
    } else {
#pragma unroll
        for (int s = 0; s < 16; ++s) {
            float4 a0 = *(const float4*)(pA + s * 16);
            float4 a1 = *(const float4*)(pA + s * 16 + 4);
            float4 b0 = *(const float4*)(pB + s * 16);
            float4 b1 = *(const float4*)(pB + s * 16 + 4);
            short8 fa = cvt8(a0, a1);
            short8 fb = cvt8(b0, b1);
            acc = __builtin_amdgcn_mfma_f32_32x32x16_bf16(fa, fb, acc, 0, 0, 0);
        }
    }

    // ---- k-half pair reduce via LDS (C layout: col=lane&31,
    //      row=(r&3)+8*(r>>2)+4*(lane>>5), verified m74/m101) ----
    float* qb = smem + q * 1024;
    if (h == 0) {
#pragma unroll
        for (int r = 0; r < 16; ++r) {
            int rl = (r & 3) + 8 * (r >> 2) + 4 * hi;
            qb[rl * 32 + lr] = acc[r];
        }
    }
    __syncthreads();
    if (h == 1) {
#pragma unroll
        for (int r = 0; r < 16; ++r) {
            int rl = (r & 3) + 8 * (r >> 2) + 4 * hi;
            qb[rl * 32 + lr] += acc[r];
        }
    }
    __syncthreads();

    // ---- remap [q][32][32] -> [64][64], write partials (float4) ----
    float* outp = partials + (size_t)gb * PSTRIDE;
    const f32x4* s4 = (const f32x4*)smem;
    f32x4* o4 = (f32x4*)outp;
    for (int e = t; e < 1024; e += 512) {
        int qq = e >> 8, rl = (e >> 3) & 31, cl = e & 7;
        o4[((qq >> 1) * 32 + rl) * 16 + (qq & 1) * 8 + cl] = s4[e];
    }
}

// ---------------------------------------------------------------------------
// Kernel 2: sum partials per feature -> K[f], zero diagonal.
// Main path (singleF < 0): grid 448; A features have 128 partial rows at
// base f*128, B features 64 rows at base 384+(f-3)*64.
// Fallback (singleF >= 0): grid 64, base 0, count by feature type.
// ---------------------------------------------------------------------------
__global__ __launch_bounds__(256) void reduce_kernel(
    const float* __restrict__ partials, float* __restrict__ K, int singleF)
{
    __shared__ double red[256];
    int f, eblk, base, count;
    if (singleF < 0) {
        f = blockIdx.x >> 6; eblk = blockIdx.x & 63;
        if (f < 3) { base = f * 128;            count = 128; }
        else       { base = 384 + (f - 3) * 64; count = 64;  }
    } else {
        f = singleF; eblk = blockIdx.x; base = 0;
        count = (f < 3) ? 128 : 64;
    }
    const int e = (eblk << 6) + (threadIdx.x & 63);
    const int jg = threadIdx.x >> 6;

    double s0 = 0.0, s1 = 0.0;
    for (int j = jg; j < count; j += 8) {
        s0 += (double)partials[(size_t)(base + j) * PSTRIDE + e];
        s1 += (double)partials[(size_t)(base + j + 4) * PSTRIDE + e];
    }
    red[threadIdx.x] = s0 + s1;
    __syncthreads();
    if (jg == 0) {
        double tot = red[threadIdx.x] + red[threadIdx.x + 64]
                   + red[threadIdx.x + 128] + red[threadIdx.x + 192];
        int rr = e >> 6, cc = e & 63;
        K[f * 4096 + e] = (rr == cc) ? 0.f : (float)tot;
    }
}

// ---------------------------------------------------------------------------
// Kernel 3 (hsic + final fused): single block, 256 threads.
// Rowsums once (fp64), then 25 pairwise unbiased HSIC, then CKA + CE -> loss.
// Same fp64 math/order as the validated split kernels.
// ---------------------------------------------------------------------------
__global__ __launch_bounds__(256) void cka_final_kernel(
    const float* __restrict__ K, const float* __restrict__ ce_rows,
    float* __restrict__ out_loss)
{
    __shared__ double rs[448];
    __shared__ double sf[8];
    __shared__ double red[256];
    __shared__ double hs[25];
    const int t = threadIdx.x;

    for (int g = t; g < 448; g += 256) {
        double s = 0.0;
        const float* kr = K + g * 64;
        for (int c2 = 0; c2 < 64; ++c2) s += (double)kr[c2];
        rs[g] = s;
    }
    __syncthreads();
    if (t < 7) {
        double s = 0.0;
        for (int r = 0; r < 64; ++r) s += rs[t * 64 + r];
        sf[t] = s;
    }
    __syncthreads();

    for (int p = 0; p < 25; ++p) {
        int i, j;
        if (p < 9) { i = p / 3; j = p % 3; }
        else       { int qq = p - 9; i = 3 + qq / 4; j = 3 + qq % 4; }
        const float* Ki = K + i * 4096;
        const float* Kj = K + j * 4096;
        double local = 0.0;
        for (int e = t; e < 4096; e += 256)
            local += (double)Ki[e] * (double)Kj[e];
        red[t] = local; __syncthreads();
        for (int s = 128; s > 0; s >>= 1) {
            if (t < s) red[t] += red[t + s];
            __syncthreads();
        }
        double tr = red[0];
        __syncthreads();
        red[t] = (t < 64) ? rs[i * 64 + t] * rs[j * 64 + t] : 0.0;
        __syncthreads();
        for (int s = 128; s > 0; s >>= 1) {
            if (t < s) red[t] += red[t + s];
            __syncthreads();
        }
        if (t == 0) {
            const double N = 64.0;
            hs[p] = (tr + sf[i] * sf[j] / ((N - 1.0) * (N - 2.0))
                     - 2.0 * red[0] / (N - 2.0)) / (N * (N - 3.0));
        }
        __syncthreads();
    }

    if (t == 0) {
        double ce = 0.0;
        for (int n = 0; n < 64; ++n) ce += (double)ce_rows[n];
        ce /= 64.0;
        double cka = 0.0;
        for (int i = 0; i < 3; ++i)
            for (int j = 0; j < 3; ++j)
                cka += hs[i * 3 + j] / sqrt(hs[i * 3 + i] * hs[j * 3 + j]);
        for (int i = 0; i < 4; ++i)
            for (int j = 0; j < 4; ++j)
                cka += hs[9 + i * 4 + j] / sqrt(hs[9 + i * 4 + i] * hs[9 + j * 4 + j]);
        out_loss[0] = (float)(ce + 0.1 * cka);
    }
}

// ---------------------------------------------------------------------------
extern "C" void kernel_launch(void* const* d_in, const int* in_sizes, int n_in,
                              void* d_out, int out_size, void* d_ws, size_t ws_size,
                              hipStream_t stream)
{
    const float* output  = (const float*)d_in[0];
    const int*   target  = (const int*)d_in[1];
    const float* feats_a = (const float*)d_in[2];
    const float* feats_b = (const float*)d_in[3];
    float* out = (float*)d_out;

    char* ws = (char*)d_ws;
    float*  K        = (float*)ws;                 // 114688 B
    float*  ce_rows  = (float*)(ws + 114688);      // 256 B
    float*  partials = (float*)(ws + 131072);

    const size_t partMain = (size_t)640 * PSTRIDE * 4;   // 10.65 MB
    const size_t mainNeed = 131072 + partMain;

    if (ws_size >= mainNeed) {
        // ---------------- one-shot path ----------------
        hipLaunchKernelGGL(gram_ce_kernel, dim3(640 + 64), dim3(512), 0, stream,
                           feats_a, feats_b, partials, 3, 4,
                           output, target, out + 1, ce_rows, 64);
        hipLaunchKernelGGL(reduce_kernel, dim3(448), dim3(256), 0, stream,
                           partials, K, -1);
    } else {
        // ---------------- per-feature fallback (~2.3 MB) ----------------
        for (int f = 0; f < 7; ++f) {
            if (f < 3) {
                const float* X = feats_a + (size_t)f * 64 * 65536;
                int ce = (f == 0) ? 64 : 0;
                hipLaunchKernelGGL(gram_ce_kernel, dim3(128 + ce), dim3(512), 0, stream,
                                   X, (const float*)nullptr, partials, 1, 0,
                                   output, target, out + 1, ce_rows, ce);
            } else {
                const float* X = feats_b + (size_t)(f - 3) * 64 * 32768;
                hipLaunchKernelGGL(gram_ce_kernel, dim3(64), dim3(512), 0, stream,
                                   (const float*)nullptr, X, partials, 0, 1,
                                   output, target, out + 1, ce_rows, 0);
            }
            hipLaunchKernelGGL(reduce_kernel, dim3(64), dim3(256), 0, stream,
                               partials, K, f);
        }
    }

    hipLaunchKernelGGL(cka_final_kernel, dim3(1), dim3(256), 0, stream,
                       K, ce_rows, out);
}

// Round 4
// 158.370 us; speedup vs baseline: 1.4382x; 1.4382x over previous
//
#include <hip/hip_runtime.h>
#include <math.h>

typedef __attribute__((ext_vector_type(8))) short short8;
typedef __attribute__((ext_vector_type(4))) float f32x4;
typedef __attribute__((ext_vector_type(16))) float f32x16;

#define PSTRIDE 4160          // partials row stride in floats (non-pow2)

// round-to-nearest-even fp32 -> bf16 bits (validated numerics, keep exact)
__device__ __forceinline__ unsigned int bf16_rn(float x) {
    unsigned int u = __float_as_uint(x);
    return (u + 0x7FFFu + ((u >> 16) & 1u)) >> 16;
}

__device__ __forceinline__ short8 cvt8(float4 a, float4 b) {
    short8 h;
    h[0] = (short)bf16_rn(a.x); h[1] = (short)bf16_rn(a.y);
    h[2] = (short)bf16_rn(a.z); h[3] = (short)bf16_rn(a.w);
    h[4] = (short)bf16_rn(b.x); h[5] = (short)bf16_rn(b.y);
    h[6] = (short)bf16_rn(b.z); h[7] = (short)bf16_rn(b.w);
    return h;
}

// ---------------------------------------------------------------------------
// Kernel 1 (gram + CE fused): 512 threads (8 waves).
// CE blocks first (blk < ceCount): per-row cross-entropy + logits copy.
// Gram blocks: one block per (feature, 512-k chunk); wave w = (khalf h=w>>2,
// quadrant q=w&3). Each wave computes its 32x32 quadrant over a 256-k window
// with mfma_f32_32x32x16_bf16, fragments loaded DIRECTLY from global fp32
// (2x float4/operand, 32 rows x 64 B line-coalesced) and converted in-reg.
// No staging LDS -> high occupancy. k-half pairs reduce via 16 KB LDS, then
// write the 64x64 partial Gram. (Validated R3: absmax 0.)
// ---------------------------------------------------------------------------
__global__ __launch_bounds__(512, 6) void gram_ce_kernel(
    const float* __restrict__ A, const float* __restrict__ B,
    float* __restrict__ partials, int nfA, int nfB,
    const float* __restrict__ logits, const int* __restrict__ target,
    float* __restrict__ out_copy, float* __restrict__ ce_rows, int ceCount)
{
    __shared__ float smem[4096];   // gram: 4x[32][32] quadrant buf; CE: red
    const int t = threadIdx.x;

    if ((int)blockIdx.x < ceCount) {
        // ------------------ CE block ------------------
        const int row = blockIdx.x;
        const float* x = logits + row * 1000;
        float m = -INFINITY;
        for (int i = t; i < 1000; i += 512) {
            float v = x[i];
            out_copy[row * 1000 + i] = v;
            m = fmaxf(m, v);
        }
        smem[t] = m; __syncthreads();
        for (int s = 256; s > 0; s >>= 1) {
            if (t < s) smem[t] = fmaxf(smem[t], smem[t + s]);
            __syncthreads();
        }
        m = smem[0];
        __syncthreads();
        float ssum = 0.f;
        for (int i = t; i < 1000; i += 512) ssum += expf(x[i] - m);
        smem[t] = ssum; __syncthreads();
        for (int s = 256; s > 0; s >>= 1) {
            if (t < s) smem[t] += smem[t + s];
            __syncthreads();
        }
        if (t == 0) {
            double lse = (double)m + log((double)smem[0]);
            int tg = target[row];
            ce_rows[row] = (float)(-((double)x[tg] - lse));
        }
        return;
    }

    // ------------------ gram block ------------------
    const int gb = blockIdx.x - ceCount;
    const int uA = nfA * 128;              // A chunk-blocks (128 x 512k /feat)
    const float* xf;
    int c, D;
    if (gb < uA) {
        int f = gb >> 7; c = gb & 127; D = 65536;
        xf = A + (size_t)f * 64 * 65536;
    } else {
        int v = gb - uA;
        int f = v >> 6; c = v & 63; D = 32768;
        xf = B + (size_t)f * 64 * 32768;
    }

    const int wave = t >> 6, lane = t & 63;
    const int q = wave & 3, h = wave >> 2;
    const int wr = q >> 1, wc = q & 1;
    const int lr = lane & 31, hi = lane >> 5;
    const int k0 = c * 512 + h * 256 + hi * 8;

    const float* pA = xf + (size_t)(wr * 32 + lr) * D + k0;
    const float* pB = xf + (size_t)(wc * 32 + lr) * D + k0;

    f32x16 acc = (f32x16)0.f;
    if (wr == wc) {
#pragma unroll
        for (int s = 0; s < 16; ++s) {
            float4 a0 = *(const float4*)(pA + s * 16);
            float4 a1 = *(const float4*)(pA + s * 16 + 4);
            short8 fa = cvt8(a0, a1);
            acc = __builtin_amdgcn_mfma_f32_32x32x16_bf16(fa, fa, acc, 0, 0, 0);
        }
    } else {
#pragma unroll
        for (int s = 0; s < 16; ++s) {
            float4 a0 = *(const float4*)(pA + s * 16);
            float4 a1 = *(const float4*)(pA + s * 16 + 4);
            float4 b0 = *(const float4*)(pB + s * 16);
            float4 b1 = *(const float4*)(pB + s * 16 + 4);
            short8 fa = cvt8(a0, a1);
            short8 fb = cvt8(b0, b1);
            acc = __builtin_amdgcn_mfma_f32_32x32x16_bf16(fa, fb, acc, 0, 0, 0);
        }
    }

    // ---- k-half pair reduce via LDS (C layout: col=lane&31,
    //      row=(r&3)+8*(r>>2)+4*(lane>>5), verified m74/m101) ----
    float* qb = smem + q * 1024;
    if (h == 0) {
#pragma unroll
        for (int r = 0; r < 16; ++r) {
            int rl = (r & 3) + 8 * (r >> 2) + 4 * hi;
            qb[rl * 32 + lr] = acc[r];
        }
    }
    __syncthreads();
    if (h == 1) {
#pragma unroll
        for (int r = 0; r < 16; ++r) {
            int rl = (r & 3) + 8 * (r >> 2) + 4 * hi;
            qb[rl * 32 + lr] += acc[r];
        }
    }
    __syncthreads();

    // ---- remap [q][32][32] -> [64][64], write partials (float4) ----
    float* outp = partials + (size_t)gb * PSTRIDE;
    const f32x4* s4 = (const f32x4*)smem;
    f32x4* o4 = (f32x4*)outp;
    for (int e = t; e < 1024; e += 512) {
        int qq = e >> 8, rl = (e >> 3) & 31, cl = e & 7;
        o4[((qq >> 1) * 32 + rl) * 16 + (qq & 1) * 8 + cl] = s4[e];
    }
}

// ---------------------------------------------------------------------------
// Kernel 2: sum partials per feature -> K[f], zero diagonal.
// Main path (singleF < 0): grid 448; A features have 128 partial rows at
// base f*128, B features 64 rows at base 384+(f-3)*64.
// Fallback (singleF >= 0): grid 64, base 0, count by feature type.
// ---------------------------------------------------------------------------
__global__ __launch_bounds__(256) void reduce_kernel(
    const float* __restrict__ partials, float* __restrict__ K, int singleF)
{
    __shared__ double red[256];
    int f, eblk, base, count;
    if (singleF < 0) {
        f = blockIdx.x >> 6; eblk = blockIdx.x & 63;
        if (f < 3) { base = f * 128;            count = 128; }
        else       { base = 384 + (f - 3) * 64; count = 64;  }
    } else {
        f = singleF; eblk = blockIdx.x; base = 0;
        count = (f < 3) ? 128 : 64;
    }
    const int e = (eblk << 6) + (threadIdx.x & 63);
    const int jg = threadIdx.x >> 6;

    double s0 = 0.0, s1 = 0.0;
    for (int j = jg; j < count; j += 8) {
        s0 += (double)partials[(size_t)(base + j) * PSTRIDE + e];
        s1 += (double)partials[(size_t)(base + j + 4) * PSTRIDE + e];
    }
    red[threadIdx.x] = s0 + s1;
    __syncthreads();
    if (jg == 0) {
        double tot = red[threadIdx.x] + red[threadIdx.x + 64]
                   + red[threadIdx.x + 128] + red[threadIdx.x + 192];
        int rr = e >> 6, cc = e & 63;
        K[f * 4096 + e] = (rr == cc) ? 0.f : (float)tot;
    }
}

// ---------------------------------------------------------------------------
// Kernel 3: one block per (i,j) pair -> unbiased HSIC in fp64.
// (Restored validated parallel version — the R3 single-block fusion was an
// 85 us serialization.)
// ---------------------------------------------------------------------------
__global__ __launch_bounds__(256) void hsic_kernel(
    const float* __restrict__ K, double* __restrict__ hsic_out)
{
    const int p = blockIdx.x;
    int i, j;
    if (p < 9) { i = p / 3; j = p % 3; }
    else       { int q = p - 9; i = 3 + q / 4; j = 3 + q % 4; }
    const float* Ki = K + i * 4096;
    const float* Kj = K + j * 4096;
    const int t = threadIdx.x;

    __shared__ double red[256];
    __shared__ double ri[64], rj[64];

    double local = 0.0;
    for (int e = t; e < 4096; e += 256)
        local += (double)Ki[e] * (double)Kj[e];
    red[t] = local; __syncthreads();
    for (int s = 128; s > 0; s >>= 1) {
        if (t < s) red[t] += red[t + s];
        __syncthreads();
    }

    if (t < 64) {
        double s = 0.0;
        for (int mc = 0; mc < 64; ++mc) s += (double)Ki[t * 64 + mc];
        ri[t] = s;
    } else if (t < 128) {
        int n = t - 64;
        double s = 0.0;
        for (int mc = 0; mc < 64; ++mc) s += (double)Kj[n * 64 + mc];
        rj[n] = s;
    }
    __syncthreads();

    if (t == 0) {
        double tr = red[0];
        double rr = 0.0, si = 0.0, sj = 0.0;
        for (int n = 0; n < 64; ++n) {
            rr += ri[n] * rj[n];
            si += ri[n];
            sj += rj[n];
        }
        const double N = 64.0;
        const double c1 = (N - 1.0) * (N - 2.0);
        const double c2 = N - 2.0;
        const double c3 = N * (N - 3.0);
        hsic_out[p] = (tr + si * sj / c1 - 2.0 * rr / c2) / c3;
    }
}

// ---------------------------------------------------------------------------
// Kernel 4: combine -> loss.
// ---------------------------------------------------------------------------
__global__ __launch_bounds__(64) void final_kernel(
    const double* __restrict__ hsic, const float* __restrict__ ce_rows,
    float* __restrict__ out_loss)
{
    if (threadIdx.x != 0) return;
    double ce = 0.0;
    for (int n = 0; n < 64; ++n) ce += (double)ce_rows[n];
    ce /= 64.0;

    double cka_total = 0.0;
    for (int i = 0; i < 3; ++i)
        for (int j = 0; j < 3; ++j)
            cka_total += hsic[i * 3 + j] / sqrt(hsic[i * 3 + i] * hsic[j * 3 + j]);
    for (int i = 0; i < 4; ++i)
        for (int j = 0; j < 4; ++j)
            cka_total += hsic[9 + i * 4 + j] / sqrt(hsic[9 + i * 4 + i] * hsic[9 + j * 4 + j]);

    out_loss[0] = (float)(ce + 0.1 * cka_total);
}

// ---------------------------------------------------------------------------
extern "C" void kernel_launch(void* const* d_in, const int* in_sizes, int n_in,
                              void* d_out, int out_size, void* d_ws, size_t ws_size,
                              hipStream_t stream)
{
    const float* output  = (const float*)d_in[0];
    const int*   target  = (const int*)d_in[1];
    const float* feats_a = (const float*)d_in[2];
    const float* feats_b = (const float*)d_in[3];
    float* out = (float*)d_out;

    char* ws = (char*)d_ws;
    float*  K        = (float*)ws;                 // 114688 B
    float*  ce_rows  = (float*)(ws + 114688);      // 256 B
    double* hsic     = (double*)(ws + 114944);     // 200 B
    float*  partials = (float*)(ws + 131072);

    const size_t partMain = (size_t)640 * PSTRIDE * 4;   // 10.65 MB
    const size_t mainNeed = 131072 + partMain;

    if (ws_size >= mainNeed) {
        // ---------------- one-shot path ----------------
        hipLaunchKernelGGL(gram_ce_kernel, dim3(640 + 64), dim3(512), 0, stream,
                           feats_a, feats_b, partials, 3, 4,
                           output, target, out + 1, ce_rows, 64);
        hipLaunchKernelGGL(reduce_kernel, dim3(448), dim3(256), 0, stream,
                           partials, K, -1);
    } else {
        // ---------------- per-feature fallback (~2.3 MB) ----------------
        for (int f = 0; f < 7; ++f) {
            if (f < 3) {
                const float* X = feats_a + (size_t)f * 64 * 65536;
                int ce = (f == 0) ? 64 : 0;
                hipLaunchKernelGGL(gram_ce_kernel, dim3(128 + ce), dim3(512), 0, stream,
                                   X, (const float*)nullptr, partials, 1, 0,
                                   output, target, out + 1, ce_rows, ce);
            } else {
                const float* X = feats_b + (size_t)(f - 3) * 64 * 32768;
                hipLaunchKernelGGL(gram_ce_kernel, dim3(64), dim3(512), 0, stream,
                                   (const float*)nullptr, X, partials, 0, 1,
                                   output, target, out + 1, ce_rows, 0);
            }
            hipLaunchKernelGGL(reduce_kernel, dim3(64), dim3(256), 0, stream,
                               partials, K, f);
        }
    }

    hipLaunchKernelGGL(hsic_kernel, dim3(25), dim3(256), 0, stream, K, hsic);
    hipLaunchKernelGGL(final_kernel, dim3(1), dim3(64), 0, stream,
                       hsic, ce_rows, out);
}